// Round 14
// baseline (192.936 us; speedup 1.0000x reference)
//
#include <hip/hip_runtime.h>
#include <hip/hip_bf16.h>
#include <stdint.h>

#define B_ 4
#define T_ 2048
#define NH 16
#define DH 64
#define DIM 1024
#define NF 3072
#define TBL 4112   // padded per-head bias table stride (floats)

typedef unsigned short u16;
typedef uint32_t u32;
typedef __bf16 bf16;
typedef bf16 bf16x8 __attribute__((ext_vector_type(8)));
typedef float f32x4 __attribute__((ext_vector_type(4)));
typedef u16 u16x8 __attribute__((ext_vector_type(8)));
typedef u16 u16x4 __attribute__((ext_vector_type(4)));

__device__ __forceinline__ u16 f2bf(float f) {
    u32 u = __builtin_bit_cast(u32, f);
    u = (u + 0x7fffu + ((u >> 16) & 1u)) >> 16;
    return (u16)u;
}

__device__ __forceinline__ float exp2f_fast(float x) {
#if __has_builtin(__builtin_amdgcn_exp2f)
    return __builtin_amdgcn_exp2f(x);
#else
    return exp2f(x);
#endif
}

#define GLOAD16(g, l)                                                          \
    __builtin_amdgcn_global_load_lds(                                          \
        (const __attribute__((address_space(1))) u32*)(g),                     \
        (__attribute__((address_space(3))) u32*)(l), 16, 0, 0)

// ---------------- glue kernels ----------------

__global__ __launch_bounds__(256) void cvt_bf16_k(const float* __restrict__ src,
                                                  u16* __restrict__ dst, int n8) {
    int i = blockIdx.x * 256 + threadIdx.x;
    if (i >= n8) return;
    const float4* s = (const float4*)src + (size_t)i * 2;
    float4 a = s[0], b = s[1];
    u16x8 o;
    o[0]=f2bf(a.x); o[1]=f2bf(a.y); o[2]=f2bf(a.z); o[3]=f2bf(a.w);
    o[4]=f2bf(b.x); o[5]=f2bf(b.y); o[6]=f2bf(b.z); o[7]=f2bf(b.w);
    *(u16x8*)(dst + (size_t)i * 8) = o;
}

// src (K x N) f32 -> dst (N' x K) bf16, transposed.
// PERM: row n (= feature f = d*48 + k*16 + h of W_qkv) is written to row
// n' = k*1024 + h*64 + d, so the QKV GEMM emits qkv in (k,h,d) feature
// order = Q/K/V slices directly (kills the reshape pass).
template <int PERM>
__global__ __launch_bounds__(256) void wcvt_t_k(const float* __restrict__ src,
                                                u16* __restrict__ dst, int K, int N) {
    __shared__ float tile[32][33];
    int n0 = blockIdx.x * 32, k0 = blockIdx.y * 32;
    int c = threadIdx.x & 31, r0 = threadIdx.x >> 5;
#pragma unroll
    for (int i = 0; i < 4; i++) {
        int r = r0 + i * 8;
        tile[r][c] = src[(size_t)(k0 + r) * N + n0 + c];
    }
    __syncthreads();
#pragma unroll
    for (int i = 0; i < 4; i++) {
        int r = r0 + i * 8;
        int n = n0 + r;
        int nd;
        if (PERM) {
            int d = n / 48, rem = n - d * 48;
            int kk = rem >> 4, h = rem & 15;
            nd = kk * 1024 + h * 64 + d;
        } else {
            nd = n;
        }
        dst[(size_t)nd * K + k0 + c] = f2bf(tile[c][r]);
    }
}

// rel_bias (4095,16) f32 -> rbF4[s][h][i] = masked_log2e_tab[h][i + s] f32,
// s = 0..3 shifted copies so any lane's 4 consecutive bias values are one
// aligned float4. tab idx > 2047 (j > qi, causal) or out of range -> -1e30.
__global__ __launch_bounds__(256) void rbt_k(const float* __restrict__ rb,
                                             float* __restrict__ rbF4) {
    int i = blockIdx.x * 256 + threadIdx.x;
    if (i >= 4 * NH * TBL) return;
    int s = i / (NH * TBL);
    int rem = i - s * (NH * TBL);
    int h = rem / TBL, d = rem - h * TBL;
    int d2 = d + s;
    rbF4[i] = (d2 <= 2047) ? rb[(size_t)d2 * NH + h] * 1.44269504f : -1e30f;
}

// V slice of qkvF (b,t, 2048 + h*64+d) -> Vt (b,h,d,t)
__global__ __launch_bounds__(256) void transpose_v_k(const u16* __restrict__ qkvF,
                                                     u16* __restrict__ Vt) {
    __shared__ __align__(16) u16 tile[64][72];
    int bh = blockIdx.y;
    int h = bh & 15, b = bh >> 4;
    int t0 = blockIdx.x * 64;
    const u16* src = qkvF + ((size_t)b * T_ + t0) * NF + 2048 + h * 64;
    for (int idx = threadIdx.x; idx < 512; idx += 256) {
        int r = idx >> 3, ch = idx & 7;
        *(u16x8*)&tile[r][ch * 8] = *(const u16x8*)&src[(size_t)r * NF + ch * 8];
    }
    __syncthreads();
    u16* dst = Vt + (size_t)bh * DH * T_ + t0;
    for (int idx = threadIdx.x; idx < 512; idx += 256) {
        int d = idx >> 3, ch = idx & 7;
        u16x8 v;
#pragma unroll
        for (int e = 0; e < 8; e++) v[e] = tile[ch * 8 + e][d];
        *(u16x8*)&dst[(size_t)d * T_ + ch * 8] = v;
    }
}

// ---------------- GEMM: C = A(MxK) * Bt(NxK)^T, 128x128 tile, BK=64 ----------------
// BK=64 halves barrier count vs BK=32 (the ~20% barrier-drain stall).
// 128B row stride would 4-way bank-conflict the fragment reads, so chunks
// are XOR-swizzled: global_load_lds SOURCE is pre-swizzled (dest stays
// linear, rule #21) and reads use pos = ch ^ (row&7) -> 2-way (free).

template <int WRITE_BF16>
__global__ __launch_bounds__(256, 2) void gemm_bt_k(const u16* __restrict__ A,
                                                    const u16* __restrict__ Bt,
                                                    void* __restrict__ Cout,
                                                    int M, int N, int K) {
    __shared__ __align__(16) u16 As[128 * 64];
    __shared__ __align__(16) u16 Bs[128 * 64];
    const int tid = threadIdx.x;
    const int wave = tid >> 6, lane = tid & 63;
    const int bm = blockIdx.x, bn = blockIdx.y;
    const int wr = (wave >> 1) * 64, wc = (wave & 1) * 64;
    const int lrow = lane & 15, g4 = lane >> 4;
    const int srow8 = lane >> 3;           // 0..7 row within an 8-row gload
    const int scs = (lane & 7) ^ srow8;    // pre-swizzled source chunk
    const u16* Ab = A + (size_t)(bm * 128 + wave * 32) * K;
    const u16* Bb = Bt + (size_t)(bn * 128 + wave * 32) * K;
    u16* AsW = As + wave * 2048;           // wave rows [w*32, w*32+32), 64 k
    u16* BsW = Bs + wave * 2048;
    f32x4 acc[4][4] = {};

    for (int k0 = 0; k0 < K; k0 += 64) {
        __syncthreads();  // previous tile fully consumed
#pragma unroll
        for (int g = 0; g < 4; g++) {
            GLOAD16(Ab + (size_t)(g * 8 + srow8) * K + k0 + scs * 8, AsW + g * 512);
            GLOAD16(Bb + (size_t)(g * 8 + srow8) * K + k0 + scs * 8, BsW + g * 512);
        }
        __syncthreads();
#pragma unroll
        for (int kk2 = 0; kk2 < 2; kk2++) {
            bf16x8 af[4], bfr[4];
#pragma unroll
            for (int i = 0; i < 4; i++)
                af[i] = *(const bf16x8*)&As[(wr + i * 16 + lrow) * 64 +
                                            (((kk2 * 4 + g4) ^ (lrow & 7)) * 8)];
#pragma unroll
            for (int j = 0; j < 4; j++)
                bfr[j] = *(const bf16x8*)&Bs[(wc + j * 16 + lrow) * 64 +
                                             (((kk2 * 4 + g4) ^ (lrow & 7)) * 8)];
#pragma unroll
            for (int i = 0; i < 4; i++)
#pragma unroll
                for (int j = 0; j < 4; j++)
                    acc[i][j] = __builtin_amdgcn_mfma_f32_16x16x32_bf16(af[i], bfr[j],
                                                                        acc[i][j], 0, 0, 0);
        }
    }

    const int crow = (lane >> 4) * 4, ccol = lane & 15;
#pragma unroll
    for (int i = 0; i < 4; i++)
#pragma unroll
        for (int j = 0; j < 4; j++) {
            int gm = bm * 128 + wr + i * 16 + crow;
            int gn = bn * 128 + wc + j * 16 + ccol;
#pragma unroll
            for (int r = 0; r < 4; r++) {
                if (WRITE_BF16)
                    ((u16*)Cout)[(size_t)(gm + r) * N + gn] = f2bf(acc[i][j][r]);
                else
                    ((float*)Cout)[(size_t)(gm + r) * N + gn] = acc[i][j][r];
            }
        }
}

// ---------------- flash attention (swapped S' = K Q^T; 128-row q-tiles) ----------------
// r13 structure (dual 16-row q-sub-blocks per wave, paired {p,15-p}, LDS K/V,
// XCD-local remap, exp2 no-max softmax). NEW: bias from GLOBAL f32 shifted
// tables (rbF4) as one float4 per (half,ni) on the idle VMEM pipe, prefetched
// right after staging-commit so QK^T hides the L2 latency. Deletes all bias
// DS reads + unpack VALU; LDS 48 -> 32 KB.
__global__ __launch_bounds__(256, 2) void flash_attn_k(const u16* __restrict__ qkvF,
                                                       const u16* __restrict__ Vt,
                                                       const float* __restrict__ rbF,
                                                       u16* __restrict__ O) {
    __shared__ __align__(16) u16 Ks[64 * 64];
    __shared__ __align__(16) u16 Vs[64 * 64];
    __shared__ __align__(16) u16 Ps[4][2][16 * 64];
    const int tid = threadIdx.x, wave = tid >> 6, lane = tid & 63;
    const int Lid = blockIdx.x;
    const int c = Lid & 7, u = Lid >> 3;
    const int bh = ((u & 7) << 3) | c;     // bh%8 == c -> XCD-local K/V
    const int pair = u >> 3;               // q-tile pair {pair, 15-pair}, 0..7
    const int h = bh & 15, b = bh >> 4;
    const int l15 = lane & 15, g4 = lane >> 4;
    const float SC2 = 0.125f * 1.44269504f;  // scale * log2e

    const size_t trow = (size_t)b * T_;
    const int srow = tid >> 2;      // 0..63
    const int sch = tid & 3;        // chunks sch, sch+4
    u16* pwA = &Ps[wave][0][0];
    u16* pwB = &Ps[wave][1][0];
    // K slice: qkvF[(b*T + t)*NF + 1024 + h*64 + d]
    const u16* kgb = &qkvF[(trow + srow) * NF + 1024 + h * 64];
    const u16* vgb = &Vt[((size_t)bh * DH + srow) * T_];

    // prefetch K/V tile for j0=0 (first tile of half 0)
    u16x8 kv0 = *(const u16x8*)&kgb[sch * 8];
    u16x8 kv1 = *(const u16x8*)&kgb[(sch + 4) * 8];
    u16x8 vv0 = *(const u16x8*)&vgb[sch * 8];
    u16x8 vv1 = *(const u16x8*)&vgb[(sch + 4) * 8];

    for (int half = 0; half < 2; half++) {
        const int blk = half ? 15 - pair : pair;   // 128-row q-tile index
        const int qbA = blk * 128 + wave * 16;     // wave's first 16-row sub-block
        const int qbB = qbA + 64;                  // second sub-block
        bf16x8 aqA[2], aqB[2];
        aqA[0] = *(const bf16x8*)&qkvF[(trow + qbA + l15) * NF + h * 64 + g4 * 8];
        aqA[1] = *(const bf16x8*)&qkvF[(trow + qbA + l15) * NF + h * 64 + 32 + g4 * 8];
        aqB[0] = *(const bf16x8*)&qkvF[(trow + qbB + l15) * NF + h * 64 + g4 * 8];
        aqB[1] = *(const bf16x8*)&qkvF[(trow + qbB + l15) * NF + h * 64 + 32 + g4 * 8];

        // global bias base pointers (per-lane, float4-aligned). idx semantics:
        // rbF[s][h][(ib0-s) + j0 + ni*16 + r] == tab[ib0 + j0 + ni*16 + r].
        const int ib0 = 2047 - l15 + g4 * 4 - qbA;   // >= 64
        const int sA = ib0 & 3;
        const float* bgA = rbF + ((size_t)(sA * NH + h)) * TBL + (ib0 - sA);
        const float* bgB = bgA - 64;   // qbB = qbA + 64, same shift class

        f32x4 oaccA[4] = {}, oaccB[4] = {};
        float lA = 0.f, lB = 0.f;

        const int jtmax = 2 * blk + 1;
        for (int jt = 0; jt <= jtmax; jt++) {
            const int j0 = jt * 64;
            __syncthreads();   // previous tile consumed
            {   // commit prefetched K tile (kv rows, d cols) and Vt tile (d rows, kv cols), XOR-swizzled
                int sw = srow & 7;
                *(u16x8*)&Ks[srow * 64 + ((sch ^ sw) * 8)] = kv0;
                *(u16x8*)&Ks[srow * 64 + (((sch + 4) ^ sw) * 8)] = kv1;
                *(u16x8*)&Vs[srow * 64 + ((sch ^ sw) * 8)] = vv0;
                *(u16x8*)&Vs[srow * 64 + (((sch + 4) ^ sw) * 8)] = vv1;
            }
            __syncthreads();
            // issue next tile's global loads now; latency hides under compute (T14)
            {
                int njt = jt + 1;
                int j0n = (njt <= jtmax) ? njt * 64 : (half == 0 ? 0 : -1);
                if (j0n >= 0) {
                    const u16* kg = kgb + (size_t)j0n * NF;
                    const u16* vg = vgb + j0n;
                    kv0 = *(const u16x8*)&kg[sch * 8];
                    kv1 = *(const u16x8*)&kg[(sch + 4) * 8];
                    vv0 = *(const u16x8*)&vg[sch * 8];
                    vv1 = *(const u16x8*)&vg[(sch + 4) * 8];
                }
            }
            // prefetch this tile's bias float4s (VMEM; consumed after QK^T)
            float4 bqA[4], bqB[4];
#pragma unroll
            for (int ni = 0; ni < 4; ni++) {
                bqA[ni] = *(const float4*)&bgA[j0 + ni * 16];
                bqB[ni] = *(const float4*)&bgB[j0 + ni * 16];
            }
            // S' = K Q^T for both q-halves: each ak read feeds 2 MFMAs
            f32x4 sA_[4], sB_[4];
#pragma unroll
            for (int ni = 0; ni < 4; ni++) {
                f32x4 z = {};
                sA_[ni] = z;
                sB_[ni] = z;
            }
            __builtin_amdgcn_s_setprio(1);
#pragma unroll
            for (int ni = 0; ni < 4; ni++) {
                int arow = ni * 16 + l15;
#pragma unroll
                for (int kk = 0; kk < 2; kk++) {
                    int ch = kk * 4 + g4;
                    bf16x8 ak = *(const bf16x8*)&Ks[arow * 64 + ((ch ^ (arow & 7)) * 8)];
                    sA_[ni] = __builtin_amdgcn_mfma_f32_16x16x32_bf16(ak, aqA[kk], sA_[ni], 0, 0, 0);
                    sB_[ni] = __builtin_amdgcn_mfma_f32_16x16x32_bf16(ak, aqB[kk], sB_[ni], 0, 0, 0);
                }
            }
            __builtin_amdgcn_s_setprio(0);
            // softmax (exp2 direct, no max-tracking) + P-write, per half
            {
                float su = 0.f;
#pragma unroll
                for (int ni = 0; ni < 4; ni++) {
                    const float* bb = (const float*)&bqA[ni];
                    float e0 = exp2f_fast(fmaf(sA_[ni][0], SC2, bb[0]));
                    float e1 = exp2f_fast(fmaf(sA_[ni][1], SC2, bb[1]));
                    float e2 = exp2f_fast(fmaf(sA_[ni][2], SC2, bb[2]));
                    float e3 = exp2f_fast(fmaf(sA_[ni][3], SC2, bb[3]));
                    su += (e0 + e1) + (e2 + e3);
                    u16x4 pk;
                    pk[0] = __builtin_bit_cast(u16, (bf16)e0);
                    pk[1] = __builtin_bit_cast(u16, (bf16)e1);
                    pk[2] = __builtin_bit_cast(u16, (bf16)e2);
                    pk[3] = __builtin_bit_cast(u16, (bf16)e3);
                    int colb = ni * 16 + g4 * 4;
                    int ch = colb >> 3, co = colb & 7;
                    *(u16x4*)&pwA[l15 * 64 + ((ch ^ (l15 & 7)) * 8) + co] = pk;
                }
                su += __shfl_xor(su, 16);
                su += __shfl_xor(su, 32);
                lA += su;
            }
            {
                float su = 0.f;
#pragma unroll
                for (int ni = 0; ni < 4; ni++) {
                    const float* bb = (const float*)&bqB[ni];
                    float e0 = exp2f_fast(fmaf(sB_[ni][0], SC2, bb[0]));
                    float e1 = exp2f_fast(fmaf(sB_[ni][1], SC2, bb[1]));
                    float e2 = exp2f_fast(fmaf(sB_[ni][2], SC2, bb[2]));
                    float e3 = exp2f_fast(fmaf(sB_[ni][3], SC2, bb[3]));
                    su += (e0 + e1) + (e2 + e3);
                    u16x4 pk;
                    pk[0] = __builtin_bit_cast(u16, (bf16)e0);
                    pk[1] = __builtin_bit_cast(u16, (bf16)e1);
                    pk[2] = __builtin_bit_cast(u16, (bf16)e2);
                    pk[3] = __builtin_bit_cast(u16, (bf16)e3);
                    int colb = ni * 16 + g4 * 4;
                    int ch = colb >> 3, co = colb & 7;
                    *(u16x4*)&pwB[l15 * 64 + ((ch ^ (l15 & 7)) * 8) + co] = pk;
                }
                su += __shfl_xor(su, 16);
                su += __shfl_xor(su, 32);
                lB += su;
            }
            // PV: each av read feeds 2 MFMAs (both halves)
            bf16x8 bpA[2], bpB[2];
#pragma unroll
            for (int kk = 0; kk < 2; kk++) {
                int ch = kk * 4 + g4;
                int off = l15 * 64 + ((ch ^ (l15 & 7)) * 8);
                bpA[kk] = *(const bf16x8*)&pwA[off];
                bpB[kk] = *(const bf16x8*)&pwB[off];
            }
            __builtin_amdgcn_s_setprio(1);
#pragma unroll
            for (int di = 0; di < 4; di++) {
                int vrow = di * 16 + l15;
#pragma unroll
                for (int kk = 0; kk < 2; kk++) {
                    int ch = kk * 4 + g4;
                    bf16x8 av = *(const bf16x8*)&Vs[vrow * 64 + ((ch ^ (vrow & 7)) * 8)];
                    oaccA[di] = __builtin_amdgcn_mfma_f32_16x16x32_bf16(av, bpA[kk], oaccA[di], 0, 0, 0);
                    oaccB[di] = __builtin_amdgcn_mfma_f32_16x16x32_bf16(av, bpB[kk], oaccB[di], 0, 0, 0);
                }
            }
            __builtin_amdgcn_s_setprio(0);
        }
        // normalize + write attnO (b, t, h*64+d) bf16; lane owns q = qb?+l15,
        // d = di*16 + g4*4 + {0..3} -> 4x 8B stores per half
        {
            float inv = 1.0f / lA;
            u16* orow = &O[((size_t)b * T_ + qbA + l15) * (NH * DH) + h * DH];
#pragma unroll
            for (int di = 0; di < 4; di++) {
                u16x4 ov;
#pragma unroll
                for (int r = 0; r < 4; r++)
                    ov[r] = __builtin_bit_cast(u16, (bf16)(oaccA[di][r] * inv));
                *(u16x4*)&orow[di * 16 + g4 * 4] = ov;
            }
        }
        {
            float inv = 1.0f / lB;
            u16* orow = &O[((size_t)b * T_ + qbB + l15) * (NH * DH) + h * DH];
#pragma unroll
            for (int di = 0; di < 4; di++) {
                u16x4 ov;
#pragma unroll
                for (int r = 0; r < 4; r++)
                    ov[r] = __builtin_bit_cast(u16, (bf16)(oaccB[di][r] * inv));
                *(u16x4*)&orow[di * 16 + g4 * 4] = ov;
            }
        }
    }
}

// ---------------- launcher ----------------

extern "C" void kernel_launch(void* const* d_in, const int* in_sizes, int n_in,
                              void* d_out, int out_size, void* d_ws, size_t ws_size,
                              hipStream_t stream) {
    const float* x    = (const float*)d_in[0];
    const float* Wqkv = (const float*)d_in[1];
    const float* W0   = (const float*)d_in[2];
    const float* rb   = (const float*)d_in[3];
    char* ws = (char*)d_ws;

    // ws layout (bytes); Vt aliases xb (dead after QKV GEMM)
    u16*   xb    = (u16*)(ws + 0);            // 16,777,216
    u16*   WqkvT = (u16*)(ws + 16777216);     //  6,291,456
    u16*   W0T   = (u16*)(ws + 23068672);     //  2,097,152
    float* rbF4  = (float*)(ws + 25165824);   //  1,056,768 (4 x 16 x 4112 f32)
    u16*   qkvF  = (u16*)(ws + 26222592);     // 50,331,648 (features in (k,h,d) order)
    u16*   attnO = (u16*)(ws + 76554240);     // 16,777,216 (must NOT alias qkvF)
    u16*   Vtb   = (u16*)(ws + 0);            // alias xb

    cvt_bf16_k<<<4096, 256, 0, stream>>>(x, xb, (B_ * T_ * DIM) / 8);
    wcvt_t_k<1><<<dim3(NF / 32, DIM / 32), 256, 0, stream>>>(Wqkv, WqkvT, DIM, NF);
    wcvt_t_k<0><<<dim3(DIM / 32, DIM / 32), 256, 0, stream>>>(W0, W0T, DIM, DIM);
    rbt_k<<<(4 * NH * TBL + 255) / 256, 256, 0, stream>>>(rb, rbF4);

    // qkvF[b*T+t][k*1024 + h*64 + d] = (x @ W_qkv) permuted via WqkvT rows
    gemm_bt_k<1><<<dim3((B_ * T_) / 128, NF / 128), 256, 0, stream>>>(
        xb, WqkvT, qkvF, B_ * T_, NF, DIM);

    transpose_v_k<<<dim3(T_ / 64, B_ * NH), 256, 0, stream>>>(qkvF, Vtb);

    flash_attn_k<<<512, 256, 0, stream>>>(qkvF, Vtb, rbF4, attnO);

    gemm_bt_k<0><<<dim3((B_ * T_) / 128, DIM / 128), 256, 0, stream>>>(
        attnO, W0T, d_out, B_ * T_, DIM, DIM);
}

// Round 15
// 182.152 us; speedup vs baseline: 1.0592x; 1.0592x over previous
//
#include <hip/hip_runtime.h>
#include <hip/hip_bf16.h>
#include <stdint.h>

#define B_ 4
#define T_ 2048
#define NH 16
#define DH 64
#define DIM 1024
#define NF 3072

typedef unsigned short u16;
typedef uint32_t u32;
typedef __bf16 bf16;
typedef bf16 bf16x8 __attribute__((ext_vector_type(8)));
typedef float f32x4 __attribute__((ext_vector_type(4)));
typedef u16 u16x8 __attribute__((ext_vector_type(8)));
typedef u16 u16x4 __attribute__((ext_vector_type(4)));

__device__ __forceinline__ u16 f2bf(float f) {
    u32 u = __builtin_bit_cast(u32, f);
    u = (u + 0x7fffu + ((u >> 16) & 1u)) >> 16;
    return (u16)u;
}

__device__ __forceinline__ float exp2f_fast(float x) {
#if __has_builtin(__builtin_amdgcn_exp2f)
    return __builtin_amdgcn_exp2f(x);
#else
    return exp2f(x);
#endif
}

#define GLOAD16(g, l)                                                          \
    __builtin_amdgcn_global_load_lds(                                          \
        (const __attribute__((address_space(1))) u32*)(g),                     \
        (__attribute__((address_space(3))) u32*)(l), 16, 0, 0)

// ---------------- glue kernels ----------------

__global__ __launch_bounds__(256) void cvt_bf16_k(const float* __restrict__ src,
                                                  u16* __restrict__ dst, int n8) {
    int i = blockIdx.x * 256 + threadIdx.x;
    if (i >= n8) return;
    const float4* s = (const float4*)src + (size_t)i * 2;
    float4 a = s[0], b = s[1];
    u16x8 o;
    o[0]=f2bf(a.x); o[1]=f2bf(a.y); o[2]=f2bf(a.z); o[3]=f2bf(a.w);
    o[4]=f2bf(b.x); o[5]=f2bf(b.y); o[6]=f2bf(b.z); o[7]=f2bf(b.w);
    *(u16x8*)(dst + (size_t)i * 8) = o;
}

// src (K x N) f32 -> dst (N' x K) bf16, transposed.
// PERM: row n (= feature f = d*48 + k*16 + h of W_qkv) is written to row
// n' = k*1024 + h*64 + d, so the QKV GEMM emits qkv in (k,h,d) feature
// order = Q/K/V slices directly (kills the reshape pass).
template <int PERM>
__global__ __launch_bounds__(256) void wcvt_t_k(const float* __restrict__ src,
                                                u16* __restrict__ dst, int K, int N) {
    __shared__ float tile[32][33];
    int n0 = blockIdx.x * 32, k0 = blockIdx.y * 32;
    int c = threadIdx.x & 31, r0 = threadIdx.x >> 5;
#pragma unroll
    for (int i = 0; i < 4; i++) {
        int r = r0 + i * 8;
        tile[r][c] = src[(size_t)(k0 + r) * N + n0 + c];
    }
    __syncthreads();
#pragma unroll
    for (int i = 0; i < 4; i++) {
        int r = r0 + i * 8;
        int n = n0 + r;
        int nd;
        if (PERM) {
            int d = n / 48, rem = n - d * 48;
            int kk = rem >> 4, h = rem & 15;
            nd = kk * 1024 + h * 64 + d;
        } else {
            nd = n;
        }
        dst[(size_t)nd * K + k0 + c] = f2bf(tile[c][r]);
    }
}

// rel_bias (4095,16) f32 -> rbT2 (16,4096) bf16 + rbT2s (16,4096) bf16
// shifted-by-one copy (dual-parity vector reads in flash). PRE-SCALED by
// log2e; causal mask folded: idx > 2047 (j > qi) -> -1e30
__global__ __launch_bounds__(256) void rbt_k(const float* __restrict__ rb,
                                             u16* __restrict__ rbT2,
                                             u16* __restrict__ rbT2s) {
    int i = blockIdx.x * 256 + threadIdx.x;
    if (i >= NH * 4096) return;
    int h = i >> 12, d = i & 4095;
    float v = (d <= 2047) ? rb[(size_t)d * NH + h] * 1.44269504f : -1e30f;
    rbT2[i] = __builtin_bit_cast(u16, (bf16)v);
    int d2 = d + 1;
    float v2 = (d2 <= 2047) ? rb[(size_t)d2 * NH + h] * 1.44269504f : -1e30f;
    rbT2s[i] = __builtin_bit_cast(u16, (bf16)v2);
}

// V slice of qkvF (b,t, 2048 + h*64+d) -> Vt (b,h,d,t)
__global__ __launch_bounds__(256) void transpose_v_k(const u16* __restrict__ qkvF,
                                                     u16* __restrict__ Vt) {
    __shared__ __align__(16) u16 tile[64][72];
    int bh = blockIdx.y;
    int h = bh & 15, b = bh >> 4;
    int t0 = blockIdx.x * 64;
    const u16* src = qkvF + ((size_t)b * T_ + t0) * NF + 2048 + h * 64;
    for (int idx = threadIdx.x; idx < 512; idx += 256) {
        int r = idx >> 3, ch = idx & 7;
        *(u16x8*)&tile[r][ch * 8] = *(const u16x8*)&src[(size_t)r * NF + ch * 8];
    }
    __syncthreads();
    u16* dst = Vt + (size_t)bh * DH * T_ + t0;
    for (int idx = threadIdx.x; idx < 512; idx += 256) {
        int d = idx >> 3, ch = idx & 7;
        u16x8 v;
#pragma unroll
        for (int e = 0; e < 8; e++) v[e] = tile[ch * 8 + e][d];
        *(u16x8*)&dst[(size_t)d * T_ + ch * 8] = v;
    }
}

// ---------------- GEMM: C = A(MxK) * Bt(NxK)^T, 128x128 tile, BK=64 ----------------
// BK=64 halves barrier count vs BK=32 (the ~20% barrier-drain stall).
// 128B row stride would 4-way bank-conflict the fragment reads, so chunks
// are XOR-swizzled: global_load_lds SOURCE is pre-swizzled (dest stays
// linear, rule #21) and reads use pos = ch ^ (row&7) -> 2-way (free).
// [r14 measured: rest-of-pipeline 110.9 -> 105.5 us with this GEMM]

template <int WRITE_BF16>
__global__ __launch_bounds__(256, 2) void gemm_bt_k(const u16* __restrict__ A,
                                                    const u16* __restrict__ Bt,
                                                    void* __restrict__ Cout,
                                                    int M, int N, int K) {
    __shared__ __align__(16) u16 As[128 * 64];
    __shared__ __align__(16) u16 Bs[128 * 64];
    const int tid = threadIdx.x;
    const int wave = tid >> 6, lane = tid & 63;
    const int bm = blockIdx.x, bn = blockIdx.y;
    const int wr = (wave >> 1) * 64, wc = (wave & 1) * 64;
    const int lrow = lane & 15, g4 = lane >> 4;
    const int srow8 = lane >> 3;           // 0..7 row within an 8-row gload
    const int scs = (lane & 7) ^ srow8;    // pre-swizzled source chunk
    const u16* Ab = A + (size_t)(bm * 128 + wave * 32) * K;
    const u16* Bb = Bt + (size_t)(bn * 128 + wave * 32) * K;
    u16* AsW = As + wave * 2048;           // wave rows [w*32, w*32+32), 64 k
    u16* BsW = Bs + wave * 2048;
    f32x4 acc[4][4] = {};

    for (int k0 = 0; k0 < K; k0 += 64) {
        __syncthreads();  // previous tile fully consumed
#pragma unroll
        for (int g = 0; g < 4; g++) {
            GLOAD16(Ab + (size_t)(g * 8 + srow8) * K + k0 + scs * 8, AsW + g * 512);
            GLOAD16(Bb + (size_t)(g * 8 + srow8) * K + k0 + scs * 8, BsW + g * 512);
        }
        __syncthreads();
#pragma unroll
        for (int kk2 = 0; kk2 < 2; kk2++) {
            bf16x8 af[4], bfr[4];
#pragma unroll
            for (int i = 0; i < 4; i++)
                af[i] = *(const bf16x8*)&As[(wr + i * 16 + lrow) * 64 +
                                            (((kk2 * 4 + g4) ^ (lrow & 7)) * 8)];
#pragma unroll
            for (int j = 0; j < 4; j++)
                bfr[j] = *(const bf16x8*)&Bs[(wc + j * 16 + lrow) * 64 +
                                             (((kk2 * 4 + g4) ^ (lrow & 7)) * 8)];
#pragma unroll
            for (int i = 0; i < 4; i++)
#pragma unroll
                for (int j = 0; j < 4; j++)
                    acc[i][j] = __builtin_amdgcn_mfma_f32_16x16x32_bf16(af[i], bfr[j],
                                                                        acc[i][j], 0, 0, 0);
        }
    }

    const int crow = (lane >> 4) * 4, ccol = lane & 15;
#pragma unroll
    for (int i = 0; i < 4; i++)
#pragma unroll
        for (int j = 0; j < 4; j++) {
            int gm = bm * 128 + wr + i * 16 + crow;
            int gn = bn * 128 + wc + j * 16 + ccol;
#pragma unroll
            for (int r = 0; r < 4; r++) {
                if (WRITE_BF16)
                    ((u16*)Cout)[(size_t)(gm + r) * N + gn] = f2bf(acc[i][j][r]);
                else
                    ((float*)Cout)[(size_t)(gm + r) * N + gn] = acc[i][j][r];
            }
        }
}

// ---------------- flash attention (swapped S' = K Q^T; 128-row q-tiles) ----------------
// r13 proven kernel (77.7 us): dual 16-row q-sub-blocks per wave (each K/V
// LDS fragment read feeds 2 MFMAs), paired {p,15-p} -> uniform 36 kv-iters,
// grid 512 XCD-local, LDS dual-parity bf16 bias tables, exp2 no-max softmax.
__global__ __launch_bounds__(256, 2) void flash_attn_k(const u16* __restrict__ qkvF,
                                                       const u16* __restrict__ Vt,
                                                       const u16* __restrict__ rbT2,
                                                       const u16* __restrict__ rbT2s,
                                                       u16* __restrict__ O) {
    __shared__ __align__(16) u16 Ks[64 * 64];
    __shared__ __align__(16) u16 Vs[64 * 64];
    __shared__ __align__(16) u16 Ps[4][2][16 * 64];
    __shared__ __align__(16) u16 rbs2a[4096];
    __shared__ __align__(16) u16 rbs2b[4096];
    const int tid = threadIdx.x, wave = tid >> 6, lane = tid & 63;
    const int Lid = blockIdx.x;
    const int c = Lid & 7, u = Lid >> 3;
    const int bh = ((u & 7) << 3) | c;     // bh%8 == c -> XCD-local K/V
    const int pair = u >> 3;               // q-tile pair {pair, 15-pair}, 0..7
    const int h = bh & 15, b = bh >> 4;
    const int l15 = lane & 15, g4 = lane >> 4;
    const float SC2 = 0.125f * 1.44269504f;  // scale * log2e

    {   // bias tables for this head (bf16, 4096-stride, 16B-aligned)
        *(u16x8*)&rbs2a[tid * 8] = *(const u16x8*)&rbT2[(size_t)h * 4096 + tid * 8];
        *(u16x8*)&rbs2a[2048 + tid * 8] = *(const u16x8*)&rbT2[(size_t)h * 4096 + 2048 + tid * 8];
        *(u16x8*)&rbs2b[tid * 8] = *(const u16x8*)&rbT2s[(size_t)h * 4096 + tid * 8];
        *(u16x8*)&rbs2b[2048 + tid * 8] = *(const u16x8*)&rbT2s[(size_t)h * 4096 + 2048 + tid * 8];
    }

    const size_t trow = (size_t)b * T_;
    const int srow = tid >> 2;      // 0..63
    const int sch = tid & 3;        // chunks sch, sch+4
    u16* pwA = &Ps[wave][0][0];
    u16* pwB = &Ps[wave][1][0];
    // K slice: qkvF[(b*T + t)*NF + 1024 + h*64 + d]
    const u16* kgb = &qkvF[(trow + srow) * NF + 1024 + h * 64];
    const u16* vgb = &Vt[((size_t)bh * DH + srow) * T_];

    // prefetch K/V tile for j0=0 (first tile of half 0)
    u16x8 kv0 = *(const u16x8*)&kgb[sch * 8];
    u16x8 kv1 = *(const u16x8*)&kgb[(sch + 4) * 8];
    u16x8 vv0 = *(const u16x8*)&vgb[sch * 8];
    u16x8 vv1 = *(const u16x8*)&vgb[(sch + 4) * 8];

    for (int half = 0; half < 2; half++) {
        const int blk = half ? 15 - pair : pair;   // 128-row q-tile index
        const int qbA = blk * 128 + wave * 16;     // wave's first 16-row sub-block
        const int qbB = qbA + 64;                  // second sub-block
        bf16x8 aqA[2], aqB[2];
        aqA[0] = *(const bf16x8*)&qkvF[(trow + qbA + l15) * NF + h * 64 + g4 * 8];
        aqA[1] = *(const bf16x8*)&qkvF[(trow + qbA + l15) * NF + h * 64 + 32 + g4 * 8];
        aqB[0] = *(const bf16x8*)&qkvF[(trow + qbB + l15) * NF + h * 64 + g4 * 8];
        aqB[1] = *(const bf16x8*)&qkvF[(trow + qbB + l15) * NF + h * 64 + 32 + g4 * 8];

        // bias base for sub-block A (element index at j0=0, ni=0, r=0); >= 64.
        // Parity is identical for A and B (qbB = qbA + 64) -> one select.
        const int ibA = 2047 - l15 + g4 * 4 - qbA;
        const u32* b32A = (const u32*)((ibA & 1) ? &rbs2b[ibA - 1] : &rbs2a[ibA]);
        const u32* b32B = b32A - 32;   // shift by -64 elements = -32 u32

        f32x4 oaccA[4] = {}, oaccB[4] = {};
        float lA = 0.f, lB = 0.f;

        const int jtmax = 2 * blk + 1;
        for (int jt = 0; jt <= jtmax; jt++) {
            const int j0 = jt * 64;
            __syncthreads();   // previous tile consumed (covers bias tables on first iter)
            {   // commit prefetched K tile (kv rows, d cols) and Vt tile (d rows, kv cols), XOR-swizzled
                int sw = srow & 7;
                *(u16x8*)&Ks[srow * 64 + ((sch ^ sw) * 8)] = kv0;
                *(u16x8*)&Ks[srow * 64 + (((sch + 4) ^ sw) * 8)] = kv1;
                *(u16x8*)&Vs[srow * 64 + ((sch ^ sw) * 8)] = vv0;
                *(u16x8*)&Vs[srow * 64 + (((sch + 4) ^ sw) * 8)] = vv1;
            }
            __syncthreads();
            // issue next tile's global loads now; latency hides under compute (T14)
            {
                int njt = jt + 1;
                int j0n = (njt <= jtmax) ? njt * 64 : (half == 0 ? 0 : -1);
                if (j0n >= 0) {
                    const u16* kg = kgb + (size_t)j0n * NF;
                    const u16* vg = vgb + j0n;
                    kv0 = *(const u16x8*)&kg[sch * 8];
                    kv1 = *(const u16x8*)&kg[(sch + 4) * 8];
                    vv0 = *(const u16x8*)&vg[sch * 8];
                    vv1 = *(const u16x8*)&vg[(sch + 4) * 8];
                }
            }
            // S' = K Q^T for both q-halves: each ak read feeds 2 MFMAs
            f32x4 sA[4], sB[4];
#pragma unroll
            for (int ni = 0; ni < 4; ni++) {
                f32x4 z = {};
                sA[ni] = z;
                sB[ni] = z;
            }
            __builtin_amdgcn_s_setprio(1);
#pragma unroll
            for (int ni = 0; ni < 4; ni++) {
                int arow = ni * 16 + l15;
#pragma unroll
                for (int kk = 0; kk < 2; kk++) {
                    int ch = kk * 4 + g4;
                    bf16x8 ak = *(const bf16x8*)&Ks[arow * 64 + ((ch ^ (arow & 7)) * 8)];
                    sA[ni] = __builtin_amdgcn_mfma_f32_16x16x32_bf16(ak, aqA[kk], sA[ni], 0, 0, 0);
                    sB[ni] = __builtin_amdgcn_mfma_f32_16x16x32_bf16(ak, aqB[kk], sB[ni], 0, 0, 0);
                }
            }
            __builtin_amdgcn_s_setprio(0);
            // softmax (exp2 direct, no max-tracking) + P-write, per half
            const int jo = j0 >> 1;
            {
                float su = 0.f;
#pragma unroll
                for (int ni = 0; ni < 4; ni++) {
                    u32 w0 = b32A[jo + ni * 8];
                    u32 w1 = b32A[jo + ni * 8 + 1];
                    float e0 = exp2f_fast(fmaf(sA[ni][0], SC2, __builtin_bit_cast(float, w0 << 16)));
                    float e1 = exp2f_fast(fmaf(sA[ni][1], SC2, __builtin_bit_cast(float, w0 & 0xffff0000u)));
                    float e2 = exp2f_fast(fmaf(sA[ni][2], SC2, __builtin_bit_cast(float, w1 << 16)));
                    float e3 = exp2f_fast(fmaf(sA[ni][3], SC2, __builtin_bit_cast(float, w1 & 0xffff0000u)));
                    su += (e0 + e1) + (e2 + e3);
                    u16x4 pk;
                    pk[0] = __builtin_bit_cast(u16, (bf16)e0);
                    pk[1] = __builtin_bit_cast(u16, (bf16)e1);
                    pk[2] = __builtin_bit_cast(u16, (bf16)e2);
                    pk[3] = __builtin_bit_cast(u16, (bf16)e3);
                    int colb = ni * 16 + g4 * 4;
                    int ch = colb >> 3, co = colb & 7;
                    *(u16x4*)&pwA[l15 * 64 + ((ch ^ (l15 & 7)) * 8) + co] = pk;
                }
                su += __shfl_xor(su, 16);
                su += __shfl_xor(su, 32);
                lA += su;
            }
            {
                float su = 0.f;
#pragma unroll
                for (int ni = 0; ni < 4; ni++) {
                    u32 w0 = b32B[jo + ni * 8];
                    u32 w1 = b32B[jo + ni * 8 + 1];
                    float e0 = exp2f_fast(fmaf(sB[ni][0], SC2, __builtin_bit_cast(float, w0 << 16)));
                    float e1 = exp2f_fast(fmaf(sB[ni][1], SC2, __builtin_bit_cast(float, w0 & 0xffff0000u)));
                    float e2 = exp2f_fast(fmaf(sB[ni][2], SC2, __builtin_bit_cast(float, w1 << 16)));
                    float e3 = exp2f_fast(fmaf(sB[ni][3], SC2, __builtin_bit_cast(float, w1 & 0xffff0000u)));
                    su += (e0 + e1) + (e2 + e3);
                    u16x4 pk;
                    pk[0] = __builtin_bit_cast(u16, (bf16)e0);
                    pk[1] = __builtin_bit_cast(u16, (bf16)e1);
                    pk[2] = __builtin_bit_cast(u16, (bf16)e2);
                    pk[3] = __builtin_bit_cast(u16, (bf16)e3);
                    int colb = ni * 16 + g4 * 4;
                    int ch = colb >> 3, co = colb & 7;
                    *(u16x4*)&pwB[l15 * 64 + ((ch ^ (l15 & 7)) * 8) + co] = pk;
                }
                su += __shfl_xor(su, 16);
                su += __shfl_xor(su, 32);
                lB += su;
            }
            // PV: each av read feeds 2 MFMAs (both halves)
            bf16x8 bpA[2], bpB[2];
#pragma unroll
            for (int kk = 0; kk < 2; kk++) {
                int ch = kk * 4 + g4;
                int off = l15 * 64 + ((ch ^ (l15 & 7)) * 8);
                bpA[kk] = *(const bf16x8*)&pwA[off];
                bpB[kk] = *(const bf16x8*)&pwB[off];
            }
            __builtin_amdgcn_s_setprio(1);
#pragma unroll
            for (int di = 0; di < 4; di++) {
                int vrow = di * 16 + l15;
#pragma unroll
                for (int kk = 0; kk < 2; kk++) {
                    int ch = kk * 4 + g4;
                    bf16x8 av = *(const bf16x8*)&Vs[vrow * 64 + ((ch ^ (vrow & 7)) * 8)];
                    oaccA[di] = __builtin_amdgcn_mfma_f32_16x16x32_bf16(av, bpA[kk], oaccA[di], 0, 0, 0);
                    oaccB[di] = __builtin_amdgcn_mfma_f32_16x16x32_bf16(av, bpB[kk], oaccB[di], 0, 0, 0);
                }
            }
            __builtin_amdgcn_s_setprio(0);
        }
        // normalize + write attnO (b, t, h*64+d) bf16; lane owns q = qb?+l15,
        // d = di*16 + g4*4 + {0..3} -> 4x 8B stores per half
        {
            float inv = 1.0f / lA;
            u16* orow = &O[((size_t)b * T_ + qbA + l15) * (NH * DH) + h * DH];
#pragma unroll
            for (int di = 0; di < 4; di++) {
                u16x4 ov;
#pragma unroll
                for (int r = 0; r < 4; r++)
                    ov[r] = __builtin_bit_cast(u16, (bf16)(oaccA[di][r] * inv));
                *(u16x4*)&orow[di * 16 + g4 * 4] = ov;
            }
        }
        {
            float inv = 1.0f / lB;
            u16* orow = &O[((size_t)b * T_ + qbB + l15) * (NH * DH) + h * DH];
#pragma unroll
            for (int di = 0; di < 4; di++) {
                u16x4 ov;
#pragma unroll
                for (int r = 0; r < 4; r++)
                    ov[r] = __builtin_bit_cast(u16, (bf16)(oaccB[di][r] * inv));
                *(u16x4*)&orow[di * 16 + g4 * 4] = ov;
            }
        }
    }
}

// ---------------- launcher ----------------

extern "C" void kernel_launch(void* const* d_in, const int* in_sizes, int n_in,
                              void* d_out, int out_size, void* d_ws, size_t ws_size,
                              hipStream_t stream) {
    const float* x    = (const float*)d_in[0];
    const float* Wqkv = (const float*)d_in[1];
    const float* W0   = (const float*)d_in[2];
    const float* rb   = (const float*)d_in[3];
    char* ws = (char*)d_ws;

    // ws layout (bytes); Vt aliases xb (dead after QKV GEMM)
    u16*   xb    = (u16*)(ws + 0);            // 16,777,216
    u16*   WqkvT = (u16*)(ws + 16777216);     //  6,291,456
    u16*   W0T   = (u16*)(ws + 23068672);     //  2,097,152
    u16*   rbT2  = (u16*)(ws + 25165824);     //    131,072 (16 x 4096 bf16)
    u16*   rbT2s = (u16*)(ws + 25296896);     //    131,072 (shifted copy)
    u16*   qkvF  = (u16*)(ws + 25559040);     // 50,331,648 (features in (k,h,d) order)
    u16*   attnO = (u16*)(ws + 75890688);     // 16,777,216 (must NOT alias qkvF)
    u16*   Vtb   = (u16*)(ws + 0);            // alias xb

    cvt_bf16_k<<<4096, 256, 0, stream>>>(x, xb, (B_ * T_ * DIM) / 8);
    wcvt_t_k<1><<<dim3(NF / 32, DIM / 32), 256, 0, stream>>>(Wqkv, WqkvT, DIM, NF);
    wcvt_t_k<0><<<dim3(DIM / 32, DIM / 32), 256, 0, stream>>>(W0, W0T, DIM, DIM);
    rbt_k<<<(NH * 4096 + 255) / 256, 256, 0, stream>>>(rb, rbT2, rbT2s);

    // qkvF[b*T+t][k*1024 + h*64 + d] = (x @ W_qkv) permuted via WqkvT rows
    gemm_bt_k<1><<<dim3((B_ * T_) / 128, NF / 128), 256, 0, stream>>>(
        xb, WqkvT, qkvF, B_ * T_, NF, DIM);

    transpose_v_k<<<dim3(T_ / 64, B_ * NH), 256, 0, stream>>>(qkvF, Vtb);

    flash_attn_k<<<512, 256, 0, stream>>>(qkvF, Vtb, rbT2, rbT2s, attnO);

    gemm_bt_k<0><<<dim3((B_ * T_) / 128, DIM / 128), 256, 0, stream>>>(
        attnO, W0T, d_out, B_ * T_, DIM, DIM);
}

// Round 16
// 177.898 us; speedup vs baseline: 1.0845x; 1.0239x over previous
//
#include <hip/hip_runtime.h>
#include <hip/hip_bf16.h>
#include <stdint.h>

#define B_ 4
#define T_ 2048
#define NH 16
#define DH 64
#define DIM 1024
#define NF 3072
#define QKS 2048   // qkF row stride (Q,K features only; V goes straight to Vt)

typedef unsigned short u16;
typedef uint32_t u32;
typedef __bf16 bf16;
typedef bf16 bf16x8 __attribute__((ext_vector_type(8)));
typedef float f32x4 __attribute__((ext_vector_type(4)));
typedef u16 u16x8 __attribute__((ext_vector_type(8)));
typedef u16 u16x4 __attribute__((ext_vector_type(4)));

__device__ __forceinline__ u16 f2bf(float f) {
    u32 u = __builtin_bit_cast(u32, f);
    u = (u + 0x7fffu + ((u >> 16) & 1u)) >> 16;
    return (u16)u;
}

__device__ __forceinline__ float exp2f_fast(float x) {
#if __has_builtin(__builtin_amdgcn_exp2f)
    return __builtin_amdgcn_exp2f(x);
#else
    return exp2f(x);
#endif
}

#define GLOAD16(g, l)                                                          \
    __builtin_amdgcn_global_load_lds(                                          \
        (const __attribute__((address_space(1))) u32*)(g),                     \
        (__attribute__((address_space(3))) u32*)(l), 16, 0, 0)

// ---------------- glue kernels ----------------

__global__ __launch_bounds__(256) void cvt_bf16_k(const float* __restrict__ src,
                                                  u16* __restrict__ dst, int n8) {
    int i = blockIdx.x * 256 + threadIdx.x;
    if (i >= n8) return;
    const float4* s = (const float4*)src + (size_t)i * 2;
    float4 a = s[0], b = s[1];
    u16x8 o;
    o[0]=f2bf(a.x); o[1]=f2bf(a.y); o[2]=f2bf(a.z); o[3]=f2bf(a.w);
    o[4]=f2bf(b.x); o[5]=f2bf(b.y); o[6]=f2bf(b.z); o[7]=f2bf(b.w);
    *(u16x8*)(dst + (size_t)i * 8) = o;
}

// src (K x N) f32 -> dst (N' x K) bf16, transposed.
// PERM: row n (= feature f = d*48 + k*16 + h of W_qkv) is written to row
// n' = k*1024 + h*64 + d: rows 0..2047 = Q,K features (QK GEMM -> qkF),
// rows 2048..3071 = V features (V GEMM -> Vt directly).
template <int PERM>
__global__ __launch_bounds__(256) void wcvt_t_k(const float* __restrict__ src,
                                                u16* __restrict__ dst, int K, int N) {
    __shared__ float tile[32][33];
    int n0 = blockIdx.x * 32, k0 = blockIdx.y * 32;
    int c = threadIdx.x & 31, r0 = threadIdx.x >> 5;
#pragma unroll
    for (int i = 0; i < 4; i++) {
        int r = r0 + i * 8;
        tile[r][c] = src[(size_t)(k0 + r) * N + n0 + c];
    }
    __syncthreads();
#pragma unroll
    for (int i = 0; i < 4; i++) {
        int r = r0 + i * 8;
        int n = n0 + r;
        int nd;
        if (PERM) {
            int d = n / 48, rem = n - d * 48;
            int kk = rem >> 4, h = rem & 15;
            nd = kk * 1024 + h * 64 + d;
        } else {
            nd = n;
        }
        dst[(size_t)nd * K + k0 + c] = f2bf(tile[c][r]);
    }
}

// rel_bias (4095,16) f32 -> rbT2 (16,4096) bf16 + rbT2s (16,4096) bf16
// shifted-by-one copy (dual-parity vector reads in flash). PRE-SCALED by
// log2e; causal mask folded: idx > 2047 (j > qi) -> -1e30
__global__ __launch_bounds__(256) void rbt_k(const float* __restrict__ rb,
                                             u16* __restrict__ rbT2,
                                             u16* __restrict__ rbT2s) {
    int i = blockIdx.x * 256 + threadIdx.x;
    if (i >= NH * 4096) return;
    int h = i >> 12, d = i & 4095;
    float v = (d <= 2047) ? rb[(size_t)d * NH + h] * 1.44269504f : -1e30f;
    rbT2[i] = __builtin_bit_cast(u16, (bf16)v);
    int d2 = d + 1;
    float v2 = (d2 <= 2047) ? rb[(size_t)d2 * NH + h] * 1.44269504f : -1e30f;
    rbT2s[i] = __builtin_bit_cast(u16, (bf16)v2);
}

// ---------------- GEMM: C = A(MxK) * Bt(NxK)^T, 128x128 tile, BK=64 ----------------
// OUTMODE: 0 = f32 C, 1 = bf16 C, 2 = V-transpose direct: swapped MFMA
// operands give C'[n][m] with m(t) on the lane axis -> Vt stores coalesce
// (32B per 16-lane group). Vt[(b*16+h)*64+d][t], f = n = h*64+d.

template <int OUTMODE>
__global__ __launch_bounds__(256, 2) void gemm_bt_k(const u16* __restrict__ A,
                                                    const u16* __restrict__ Bt,
                                                    void* __restrict__ Cout,
                                                    int M, int N, int K) {
    __shared__ __align__(16) u16 As[128 * 64];
    __shared__ __align__(16) u16 Bs[128 * 64];
    const int tid = threadIdx.x;
    const int wave = tid >> 6, lane = tid & 63;
    const int bm = blockIdx.x, bn = blockIdx.y;
    const int wr = (wave >> 1) * 64, wc = (wave & 1) * 64;
    const int lrow = lane & 15, g4 = lane >> 4;
    const int srow8 = lane >> 3;           // 0..7 row within an 8-row gload
    const int scs = (lane & 7) ^ srow8;    // pre-swizzled source chunk
    const u16* Ab = A + (size_t)(bm * 128 + wave * 32) * K;
    const u16* Bb = Bt + (size_t)(bn * 128 + wave * 32) * K;
    u16* AsW = As + wave * 2048;           // wave rows [w*32, w*32+32), 64 k
    u16* BsW = Bs + wave * 2048;
    f32x4 acc[4][4] = {};

    for (int k0 = 0; k0 < K; k0 += 64) {
        __syncthreads();  // previous tile fully consumed
#pragma unroll
        for (int g = 0; g < 4; g++) {
            GLOAD16(Ab + (size_t)(g * 8 + srow8) * K + k0 + scs * 8, AsW + g * 512);
            GLOAD16(Bb + (size_t)(g * 8 + srow8) * K + k0 + scs * 8, BsW + g * 512);
        }
        __syncthreads();
#pragma unroll
        for (int kk2 = 0; kk2 < 2; kk2++) {
            bf16x8 af[4], bfr[4];
#pragma unroll
            for (int i = 0; i < 4; i++)
                af[i] = *(const bf16x8*)&As[(wr + i * 16 + lrow) * 64 +
                                            (((kk2 * 4 + g4) ^ (lrow & 7)) * 8)];
#pragma unroll
            for (int j = 0; j < 4; j++)
                bfr[j] = *(const bf16x8*)&Bs[(wc + j * 16 + lrow) * 64 +
                                             (((kk2 * 4 + g4) ^ (lrow & 7)) * 8)];
#pragma unroll
            for (int i = 0; i < 4; i++)
#pragma unroll
                for (int j = 0; j < 4; j++) {
                    if (OUTMODE == 2)
                        acc[i][j] = __builtin_amdgcn_mfma_f32_16x16x32_bf16(
                            bfr[j], af[i], acc[i][j], 0, 0, 0);
                    else
                        acc[i][j] = __builtin_amdgcn_mfma_f32_16x16x32_bf16(
                            af[i], bfr[j], acc[i][j], 0, 0, 0);
                }
        }
    }

    const int crow = (lane >> 4) * 4, ccol = lane & 15;
    if (OUTMODE == 2) {
        // C'[n][m]: lane col = m (t), rows = n (V feature f = h*64+d).
        u16* Vt = (u16*)Cout;
#pragma unroll
        for (int i = 0; i < 4; i++)
#pragma unroll
            for (int j = 0; j < 4; j++) {
                int gm = bm * 128 + wr + i * 16 + ccol;   // token index
                int b = gm >> 11, tt = gm & 2047;
#pragma unroll
                for (int r = 0; r < 4; r++) {
                    int f = bn * 128 + wc + j * 16 + crow + r;  // h*64+d
                    int h = f >> 6, d = f & 63;
                    Vt[(((size_t)(b * NH + h)) * DH + d) * T_ + tt] =
                        f2bf(acc[i][j][r]);
                }
            }
    } else {
#pragma unroll
        for (int i = 0; i < 4; i++)
#pragma unroll
            for (int j = 0; j < 4; j++) {
                int gm = bm * 128 + wr + i * 16 + crow;
                int gn = bn * 128 + wc + j * 16 + ccol;
#pragma unroll
                for (int r = 0; r < 4; r++) {
                    if (OUTMODE == 1)
                        ((u16*)Cout)[(size_t)(gm + r) * N + gn] = f2bf(acc[i][j][r]);
                    else
                        ((float*)Cout)[(size_t)(gm + r) * N + gn] = acc[i][j][r];
                }
            }
    }
}

// ---------------- flash attention (swapped S' = K Q^T; 128-row q-tiles) ----------------
// r13/r15 proven kernel (77.7 us): dual 16-row q-sub-blocks per wave (each K/V
// LDS fragment read feeds 2 MFMAs), paired {p,15-p} -> uniform 36 kv-iters,
// grid 512 XCD-local, LDS dual-parity bf16 bias tables, exp2 no-max softmax.
// Q/K now read from qkF (stride QKS=2048: Q at h*64, K at 1024+h*64).
__global__ __launch_bounds__(256, 2) void flash_attn_k(const u16* __restrict__ qkF,
                                                       const u16* __restrict__ Vt,
                                                       const u16* __restrict__ rbT2,
                                                       const u16* __restrict__ rbT2s,
                                                       u16* __restrict__ O) {
    __shared__ __align__(16) u16 Ks[64 * 64];
    __shared__ __align__(16) u16 Vs[64 * 64];
    __shared__ __align__(16) u16 Ps[4][2][16 * 64];
    __shared__ __align__(16) u16 rbs2a[4096];
    __shared__ __align__(16) u16 rbs2b[4096];
    const int tid = threadIdx.x, wave = tid >> 6, lane = tid & 63;
    const int Lid = blockIdx.x;
    const int c = Lid & 7, u = Lid >> 3;
    const int bh = ((u & 7) << 3) | c;     // bh%8 == c -> XCD-local K/V
    const int pair = u >> 3;               // q-tile pair {pair, 15-pair}, 0..7
    const int h = bh & 15, b = bh >> 4;
    const int l15 = lane & 15, g4 = lane >> 4;
    const float SC2 = 0.125f * 1.44269504f;  // scale * log2e

    {   // bias tables for this head (bf16, 4096-stride, 16B-aligned)
        *(u16x8*)&rbs2a[tid * 8] = *(const u16x8*)&rbT2[(size_t)h * 4096 + tid * 8];
        *(u16x8*)&rbs2a[2048 + tid * 8] = *(const u16x8*)&rbT2[(size_t)h * 4096 + 2048 + tid * 8];
        *(u16x8*)&rbs2b[tid * 8] = *(const u16x8*)&rbT2s[(size_t)h * 4096 + tid * 8];
        *(u16x8*)&rbs2b[2048 + tid * 8] = *(const u16x8*)&rbT2s[(size_t)h * 4096 + 2048 + tid * 8];
    }

    const size_t trow = (size_t)b * T_;
    const int srow = tid >> 2;      // 0..63
    const int sch = tid & 3;        // chunks sch, sch+4
    u16* pwA = &Ps[wave][0][0];
    u16* pwB = &Ps[wave][1][0];
    // K slice: qkF[(b*T + t)*QKS + 1024 + h*64 + d]
    const u16* kgb = &qkF[(trow + srow) * QKS + 1024 + h * 64];
    const u16* vgb = &Vt[((size_t)bh * DH + srow) * T_];

    // prefetch K/V tile for j0=0 (first tile of half 0)
    u16x8 kv0 = *(const u16x8*)&kgb[sch * 8];
    u16x8 kv1 = *(const u16x8*)&kgb[(sch + 4) * 8];
    u16x8 vv0 = *(const u16x8*)&vgb[sch * 8];
    u16x8 vv1 = *(const u16x8*)&vgb[(sch + 4) * 8];

    for (int half = 0; half < 2; half++) {
        const int blk = half ? 15 - pair : pair;   // 128-row q-tile index
        const int qbA = blk * 128 + wave * 16;     // wave's first 16-row sub-block
        const int qbB = qbA + 64;                  // second sub-block
        bf16x8 aqA[2], aqB[2];
        aqA[0] = *(const bf16x8*)&qkF[(trow + qbA + l15) * QKS + h * 64 + g4 * 8];
        aqA[1] = *(const bf16x8*)&qkF[(trow + qbA + l15) * QKS + h * 64 + 32 + g4 * 8];
        aqB[0] = *(const bf16x8*)&qkF[(trow + qbB + l15) * QKS + h * 64 + g4 * 8];
        aqB[1] = *(const bf16x8*)&qkF[(trow + qbB + l15) * QKS + h * 64 + 32 + g4 * 8];

        // bias base for sub-block A (element index at j0=0, ni=0, r=0); >= 64.
        // Parity is identical for A and B (qbB = qbA + 64) -> one select.
        const int ibA = 2047 - l15 + g4 * 4 - qbA;
        const u32* b32A = (const u32*)((ibA & 1) ? &rbs2b[ibA - 1] : &rbs2a[ibA]);
        const u32* b32B = b32A - 32;   // shift by -64 elements = -32 u32

        f32x4 oaccA[4] = {}, oaccB[4] = {};
        float lA = 0.f, lB = 0.f;

        const int jtmax = 2 * blk + 1;
        for (int jt = 0; jt <= jtmax; jt++) {
            const int j0 = jt * 64;
            __syncthreads();   // previous tile consumed (covers bias tables on first iter)
            {   // commit prefetched K tile (kv rows, d cols) and Vt tile (d rows, kv cols), XOR-swizzled
                int sw = srow & 7;
                *(u16x8*)&Ks[srow * 64 + ((sch ^ sw) * 8)] = kv0;
                *(u16x8*)&Ks[srow * 64 + (((sch + 4) ^ sw) * 8)] = kv1;
                *(u16x8*)&Vs[srow * 64 + ((sch ^ sw) * 8)] = vv0;
                *(u16x8*)&Vs[srow * 64 + (((sch + 4) ^ sw) * 8)] = vv1;
            }
            __syncthreads();
            // issue next tile's global loads now; latency hides under compute (T14)
            {
                int njt = jt + 1;
                int j0n = (njt <= jtmax) ? njt * 64 : (half == 0 ? 0 : -1);
                if (j0n >= 0) {
                    const u16* kg = kgb + (size_t)j0n * QKS;
                    const u16* vg = vgb + j0n;
                    kv0 = *(const u16x8*)&kg[sch * 8];
                    kv1 = *(const u16x8*)&kg[(sch + 4) * 8];
                    vv0 = *(const u16x8*)&vg[sch * 8];
                    vv1 = *(const u16x8*)&vg[(sch + 4) * 8];
                }
            }
            // S' = K Q^T for both q-halves: each ak read feeds 2 MFMAs
            f32x4 sA[4], sB[4];
#pragma unroll
            for (int ni = 0; ni < 4; ni++) {
                f32x4 z = {};
                sA[ni] = z;
                sB[ni] = z;
            }
            __builtin_amdgcn_s_setprio(1);
#pragma unroll
            for (int ni = 0; ni < 4; ni++) {
                int arow = ni * 16 + l15;
#pragma unroll
                for (int kk = 0; kk < 2; kk++) {
                    int ch = kk * 4 + g4;
                    bf16x8 ak = *(const bf16x8*)&Ks[arow * 64 + ((ch ^ (arow & 7)) * 8)];
                    sA[ni] = __builtin_amdgcn_mfma_f32_16x16x32_bf16(ak, aqA[kk], sA[ni], 0, 0, 0);
                    sB[ni] = __builtin_amdgcn_mfma_f32_16x16x32_bf16(ak, aqB[kk], sB[ni], 0, 0, 0);
                }
            }
            __builtin_amdgcn_s_setprio(0);
            // softmax (exp2 direct, no max-tracking) + P-write, per half
            const int jo = j0 >> 1;
            {
                float su = 0.f;
#pragma unroll
                for (int ni = 0; ni < 4; ni++) {
                    u32 w0 = b32A[jo + ni * 8];
                    u32 w1 = b32A[jo + ni * 8 + 1];
                    float e0 = exp2f_fast(fmaf(sA[ni][0], SC2, __builtin_bit_cast(float, w0 << 16)));
                    float e1 = exp2f_fast(fmaf(sA[ni][1], SC2, __builtin_bit_cast(float, w0 & 0xffff0000u)));
                    float e2 = exp2f_fast(fmaf(sA[ni][2], SC2, __builtin_bit_cast(float, w1 << 16)));
                    float e3 = exp2f_fast(fmaf(sA[ni][3], SC2, __builtin_bit_cast(float, w1 & 0xffff0000u)));
                    su += (e0 + e1) + (e2 + e3);
                    u16x4 pk;
                    pk[0] = __builtin_bit_cast(u16, (bf16)e0);
                    pk[1] = __builtin_bit_cast(u16, (bf16)e1);
                    pk[2] = __builtin_bit_cast(u16, (bf16)e2);
                    pk[3] = __builtin_bit_cast(u16, (bf16)e3);
                    int colb = ni * 16 + g4 * 4;
                    int ch = colb >> 3, co = colb & 7;
                    *(u16x4*)&pwA[l15 * 64 + ((ch ^ (l15 & 7)) * 8) + co] = pk;
                }
                su += __shfl_xor(su, 16);
                su += __shfl_xor(su, 32);
                lA += su;
            }
            {
                float su = 0.f;
#pragma unroll
                for (int ni = 0; ni < 4; ni++) {
                    u32 w0 = b32B[jo + ni * 8];
                    u32 w1 = b32B[jo + ni * 8 + 1];
                    float e0 = exp2f_fast(fmaf(sB[ni][0], SC2, __builtin_bit_cast(float, w0 << 16)));
                    float e1 = exp2f_fast(fmaf(sB[ni][1], SC2, __builtin_bit_cast(float, w0 & 0xffff0000u)));
                    float e2 = exp2f_fast(fmaf(sB[ni][2], SC2, __builtin_bit_cast(float, w1 << 16)));
                    float e3 = exp2f_fast(fmaf(sB[ni][3], SC2, __builtin_bit_cast(float, w1 & 0xffff0000u)));
                    su += (e0 + e1) + (e2 + e3);
                    u16x4 pk;
                    pk[0] = __builtin_bit_cast(u16, (bf16)e0);
                    pk[1] = __builtin_bit_cast(u16, (bf16)e1);
                    pk[2] = __builtin_bit_cast(u16, (bf16)e2);
                    pk[3] = __builtin_bit_cast(u16, (bf16)e3);
                    int colb = ni * 16 + g4 * 4;
                    int ch = colb >> 3, co = colb & 7;
                    *(u16x4*)&pwB[l15 * 64 + ((ch ^ (l15 & 7)) * 8) + co] = pk;
                }
                su += __shfl_xor(su, 16);
                su += __shfl_xor(su, 32);
                lB += su;
            }
            // PV: each av read feeds 2 MFMAs (both halves)
            bf16x8 bpA[2], bpB[2];
#pragma unroll
            for (int kk = 0; kk < 2; kk++) {
                int ch = kk * 4 + g4;
                int off = l15 * 64 + ((ch ^ (l15 & 7)) * 8);
                bpA[kk] = *(const bf16x8*)&pwA[off];
                bpB[kk] = *(const bf16x8*)&pwB[off];
            }
            __builtin_amdgcn_s_setprio(1);
#pragma unroll
            for (int di = 0; di < 4; di++) {
                int vrow = di * 16 + l15;
#pragma unroll
                for (int kk = 0; kk < 2; kk++) {
                    int ch = kk * 4 + g4;
                    bf16x8 av = *(const bf16x8*)&Vs[vrow * 64 + ((ch ^ (vrow & 7)) * 8)];
                    oaccA[di] = __builtin_amdgcn_mfma_f32_16x16x32_bf16(av, bpA[kk], oaccA[di], 0, 0, 0);
                    oaccB[di] = __builtin_amdgcn_mfma_f32_16x16x32_bf16(av, bpB[kk], oaccB[di], 0, 0, 0);
                }
            }
            __builtin_amdgcn_s_setprio(0);
        }
        // normalize + write attnO (b, t, h*64+d) bf16; lane owns q = qb?+l15,
        // d = di*16 + g4*4 + {0..3} -> 4x 8B stores per half
        {
            float inv = 1.0f / lA;
            u16* orow = &O[((size_t)b * T_ + qbA + l15) * (NH * DH) + h * DH];
#pragma unroll
            for (int di = 0; di < 4; di++) {
                u16x4 ov;
#pragma unroll
                for (int r = 0; r < 4; r++)
                    ov[r] = __builtin_bit_cast(u16, (bf16)(oaccA[di][r] * inv));
                *(u16x4*)&orow[di * 16 + g4 * 4] = ov;
            }
        }
        {
            float inv = 1.0f / lB;
            u16* orow = &O[((size_t)b * T_ + qbB + l15) * (NH * DH) + h * DH];
#pragma unroll
            for (int di = 0; di < 4; di++) {
                u16x4 ov;
#pragma unroll
                for (int r = 0; r < 4; r++)
                    ov[r] = __builtin_bit_cast(u16, (bf16)(oaccB[di][r] * inv));
                *(u16x4*)&orow[di * 16 + g4 * 4] = ov;
            }
        }
    }
}

// ---------------- launcher ----------------

extern "C" void kernel_launch(void* const* d_in, const int* in_sizes, int n_in,
                              void* d_out, int out_size, void* d_ws, size_t ws_size,
                              hipStream_t stream) {
    const float* x    = (const float*)d_in[0];
    const float* Wqkv = (const float*)d_in[1];
    const float* W0   = (const float*)d_in[2];
    const float* rb   = (const float*)d_in[3];
    char* ws = (char*)d_ws;

    // ws layout (bytes); no aliasing (xb live until V-GEMM; qkF live through flash)
    u16*   xb    = (u16*)(ws + 0);            // 16,777,216
    u16*   WqkvT = (u16*)(ws + 16777216);     //  6,291,456
    u16*   W0T   = (u16*)(ws + 23068672);     //  2,097,152
    u16*   rbT2  = (u16*)(ws + 25165824);     //    131,072 (16 x 4096 bf16)
    u16*   rbT2s = (u16*)(ws + 25296896);     //    131,072 (shifted copy)
    u16*   qkF   = (u16*)(ws + 25427968);     // 33,554,432 (Q,K features, stride 2048)
    u16*   attnO = (u16*)(ws + 58982400);     // 16,777,216
    u16*   Vtb   = (u16*)(ws + 75759616);     // 16,777,216 -> total 92,536,832

    cvt_bf16_k<<<4096, 256, 0, stream>>>(x, xb, (B_ * T_ * DIM) / 8);
    wcvt_t_k<1><<<dim3(NF / 32, DIM / 32), 256, 0, stream>>>(Wqkv, WqkvT, DIM, NF);
    wcvt_t_k<0><<<dim3(DIM / 32, DIM / 32), 256, 0, stream>>>(W0, W0T, DIM, DIM);
    rbt_k<<<(NH * 4096 + 255) / 256, 256, 0, stream>>>(rb, rbT2, rbT2s);

    // QK GEMM: qkF[b*T+t][k*1024 + h*64 + d] for k in {0,1}
    gemm_bt_k<1><<<dim3((B_ * T_) / 128, QKS / 128), 256, 0, stream>>>(
        xb, WqkvT, qkF, B_ * T_, QKS, DIM);

    // V GEMM: writes Vt[(b*16+h)*64+d][t] directly (swapped-operand epilogue)
    gemm_bt_k<2><<<dim3((B_ * T_) / 128, (NF - QKS) / 128), 256, 0, stream>>>(
        xb, WqkvT + (size_t)QKS * DIM, Vtb, B_ * T_, NF - QKS, DIM);

    flash_attn_k<<<512, 256, 0, stream>>>(qkF, Vtb, rbT2, rbT2s, attnO);

    gemm_bt_k<0><<<dim3((B_ * T_) / 128, DIM / 128), 256, 0, stream>>>(
        attnO, W0T, d_out, B_ * T_, DIM, DIM);
}

// Round 17
// 167.232 us; speedup vs baseline: 1.1537x; 1.0638x over previous
//
#include <hip/hip_runtime.h>
#include <hip/hip_bf16.h>
#include <stdint.h>

#define B_ 4
#define T_ 2048
#define NH 16
#define DH 64
#define DIM 1024
#define NF 3072
#define QKS 2048   // qkF row stride (Q,K features only; V goes straight to Vt)

typedef unsigned short u16;
typedef uint32_t u32;
typedef __bf16 bf16;
typedef bf16 bf16x8 __attribute__((ext_vector_type(8)));
typedef float f32x4 __attribute__((ext_vector_type(4)));
typedef u16 u16x8 __attribute__((ext_vector_type(8)));
typedef u16 u16x4 __attribute__((ext_vector_type(4)));

__device__ __forceinline__ u16 f2bf(float f) {
    u32 u = __builtin_bit_cast(u32, f);
    u = (u + 0x7fffu + ((u >> 16) & 1u)) >> 16;
    return (u16)u;
}

__device__ __forceinline__ float exp2f_fast(float x) {
#if __has_builtin(__builtin_amdgcn_exp2f)
    return __builtin_amdgcn_exp2f(x);
#else
    return exp2f(x);
#endif
}

#define GLOAD16(g, l)                                                          \
    __builtin_amdgcn_global_load_lds(                                          \
        (const __attribute__((address_space(1))) u32*)(g),                     \
        (__attribute__((address_space(3))) u32*)(l), 16, 0, 0)

// ---------------- glue kernels ----------------

__global__ __launch_bounds__(256) void cvt_bf16_k(const float* __restrict__ src,
                                                  u16* __restrict__ dst, int n8) {
    int i = blockIdx.x * 256 + threadIdx.x;
    if (i >= n8) return;
    const float4* s = (const float4*)src + (size_t)i * 2;
    float4 a = s[0], b = s[1];
    u16x8 o;
    o[0]=f2bf(a.x); o[1]=f2bf(a.y); o[2]=f2bf(a.z); o[3]=f2bf(a.w);
    o[4]=f2bf(b.x); o[5]=f2bf(b.y); o[6]=f2bf(b.z); o[7]=f2bf(b.w);
    *(u16x8*)(dst + (size_t)i * 8) = o;
}

// src (K x N) f32 -> dst (N' x K) bf16, transposed.
// PERM: row n (= feature f = d*48 + k*16 + h of W_qkv) is written to row
// n' = k*1024 + h*64 + d: rows 0..2047 = Q,K features (-> qkF),
// rows 2048..3071 = V features (-> Vt directly).
template <int PERM>
__global__ __launch_bounds__(256) void wcvt_t_k(const float* __restrict__ src,
                                                u16* __restrict__ dst, int K, int N) {
    __shared__ float tile[32][33];
    int n0 = blockIdx.x * 32, k0 = blockIdx.y * 32;
    int c = threadIdx.x & 31, r0 = threadIdx.x >> 5;
#pragma unroll
    for (int i = 0; i < 4; i++) {
        int r = r0 + i * 8;
        tile[r][c] = src[(size_t)(k0 + r) * N + n0 + c];
    }
    __syncthreads();
#pragma unroll
    for (int i = 0; i < 4; i++) {
        int r = r0 + i * 8;
        int n = n0 + r;
        int nd;
        if (PERM) {
            int d = n / 48, rem = n - d * 48;
            int kk = rem >> 4, h = rem & 15;
            nd = kk * 1024 + h * 64 + d;
        } else {
            nd = n;
        }
        dst[(size_t)nd * K + k0 + c] = f2bf(tile[c][r]);
    }
}

// rel_bias (4095,16) f32 -> rbT2 (16,4096) bf16 + rbT2s (16,4096) bf16
// shifted-by-one copy (dual-parity vector reads in flash). PRE-SCALED by
// log2e; causal mask folded: idx > 2047 (j > qi) -> -1e30
__global__ __launch_bounds__(256) void rbt_k(const float* __restrict__ rb,
                                             u16* __restrict__ rbT2,
                                             u16* __restrict__ rbT2s) {
    int i = blockIdx.x * 256 + threadIdx.x;
    if (i >= NH * 4096) return;
    int h = i >> 12, d = i & 4095;
    float v = (d <= 2047) ? rb[(size_t)d * NH + h] * 1.44269504f : -1e30f;
    rbT2[i] = __builtin_bit_cast(u16, (bf16)v);
    int d2 = d + 1;
    float v2 = (d2 <= 2047) ? rb[(size_t)d2 * NH + h] * 1.44269504f : -1e30f;
    rbT2s[i] = __builtin_bit_cast(u16, (bf16)v2);
}

// ---------------- GEMM: C = A(MxK) * Bt(NxK)^T, 128x128 tile, BK=64 ----------------
// OUTMODE 0: f32 C (out-proj). OUTMODE 1: merged QKV producer — bn<16 writes
// bf16 qkF (stride N=QKS); bn>=16 uses swapped MFMA operands so C'[n][m] has
// t on the lane axis and writes Vt[(b*16+h)*64+d][t] directly (coalesced).

template <int OUTMODE>
__global__ __launch_bounds__(256, 2) void gemm_bt_k(const u16* __restrict__ A,
                                                    const u16* __restrict__ Bt,
                                                    void* __restrict__ Cout,
                                                    u16* __restrict__ Vt,
                                                    int M, int N, int K) {
    __shared__ __align__(16) u16 As[128 * 64];
    __shared__ __align__(16) u16 Bs[128 * 64];
    const int tid = threadIdx.x;
    const int wave = tid >> 6, lane = tid & 63;
    const int bm = blockIdx.x, bn = blockIdx.y;
    const int wr = (wave >> 1) * 64, wc = (wave & 1) * 64;
    const int lrow = lane & 15, g4 = lane >> 4;
    const int srow8 = lane >> 3;           // 0..7 row within an 8-row gload
    const int scs = (lane & 7) ^ srow8;    // pre-swizzled source chunk
    const u16* Ab = A + (size_t)(bm * 128 + wave * 32) * K;
    const u16* Bb = Bt + (size_t)(bn * 128 + wave * 32) * K;
    u16* AsW = As + wave * 2048;           // wave rows [w*32, w*32+32), 64 k
    u16* BsW = Bs + wave * 2048;
    const bool vt = (OUTMODE == 1) && (bn >= 16);
    f32x4 acc[4][4] = {};

    for (int k0 = 0; k0 < K; k0 += 64) {
        __syncthreads();  // previous tile fully consumed
#pragma unroll
        for (int g = 0; g < 4; g++) {
            GLOAD16(Ab + (size_t)(g * 8 + srow8) * K + k0 + scs * 8, AsW + g * 512);
            GLOAD16(Bb + (size_t)(g * 8 + srow8) * K + k0 + scs * 8, BsW + g * 512);
        }
        __syncthreads();
#pragma unroll
        for (int kk2 = 0; kk2 < 2; kk2++) {
            bf16x8 af[4], bfr[4];
#pragma unroll
            for (int i = 0; i < 4; i++)
                af[i] = *(const bf16x8*)&As[(wr + i * 16 + lrow) * 64 +
                                            (((kk2 * 4 + g4) ^ (lrow & 7)) * 8)];
#pragma unroll
            for (int j = 0; j < 4; j++)
                bfr[j] = *(const bf16x8*)&Bs[(wc + j * 16 + lrow) * 64 +
                                             (((kk2 * 4 + g4) ^ (lrow & 7)) * 8)];
            if (vt) {
#pragma unroll
                for (int i = 0; i < 4; i++)
#pragma unroll
                    for (int j = 0; j < 4; j++)
                        acc[i][j] = __builtin_amdgcn_mfma_f32_16x16x32_bf16(
                            bfr[j], af[i], acc[i][j], 0, 0, 0);
            } else {
#pragma unroll
                for (int i = 0; i < 4; i++)
#pragma unroll
                    for (int j = 0; j < 4; j++)
                        acc[i][j] = __builtin_amdgcn_mfma_f32_16x16x32_bf16(
                            af[i], bfr[j], acc[i][j], 0, 0, 0);
            }
        }
    }

    const int crow = (lane >> 4) * 4, ccol = lane & 15;
    if (vt) {
        // C'[n][m]: lane col = m (t), rows = n (V feature f = h*64+d).
#pragma unroll
        for (int i = 0; i < 4; i++)
#pragma unroll
            for (int j = 0; j < 4; j++) {
                int gm = bm * 128 + wr + i * 16 + ccol;   // token index
                int b = gm >> 11, tt = gm & 2047;
#pragma unroll
                for (int r = 0; r < 4; r++) {
                    int f = (bn - 16) * 128 + wc + j * 16 + crow + r;  // h*64+d
                    int h = f >> 6, d = f & 63;
                    Vt[(((size_t)(b * NH + h)) * DH + d) * T_ + tt] =
                        f2bf(acc[i][j][r]);
                }
            }
    } else {
#pragma unroll
        for (int i = 0; i < 4; i++)
#pragma unroll
            for (int j = 0; j < 4; j++) {
                int gm = bm * 128 + wr + i * 16 + crow;
                int gn = bn * 128 + wc + j * 16 + ccol;
#pragma unroll
                for (int r = 0; r < 4; r++) {
                    if (OUTMODE == 1)
                        ((u16*)Cout)[(size_t)(gm + r) * N + gn] = f2bf(acc[i][j][r]);
                    else
                        ((float*)Cout)[(size_t)(gm + r) * N + gn] = acc[i][j][r];
                }
            }
    }
}

// ---------------- flash attention (swapped S' = K Q^T; 128-row q-tiles) ----------------
// r15 structure (dual 16-row q-sub-blocks per wave, paired {p,15-p}, XCD-local
// remap, dual-parity bf16 bias tables, exp2 no-max softmax). NEW: K/V LDS
// DOUBLE-BUFFER -> ONE barrier per iteration (was 2). Commit of tile jt+1
// goes to buf[cur^1] after computing from buf[cur]; iter-end barrier fences
// next iter's reads. Ps is per-wave (no barrier); rb covered by prologue
// barrier. LDS 64KB (2 blocks/CU at grid 512, unchanged).
__global__ __launch_bounds__(256, 2) void flash_attn_k(const u16* __restrict__ qkF,
                                                       const u16* __restrict__ Vt,
                                                       const u16* __restrict__ rbT2,
                                                       const u16* __restrict__ rbT2s,
                                                       u16* __restrict__ O) {
    __shared__ __align__(16) u16 Ks[2][64 * 64];
    __shared__ __align__(16) u16 Vs[2][64 * 64];
    __shared__ __align__(16) u16 Ps[4][2][16 * 64];
    __shared__ __align__(16) u16 rbs2a[4096];
    __shared__ __align__(16) u16 rbs2b[4096];
    const int tid = threadIdx.x, wave = tid >> 6, lane = tid & 63;
    const int Lid = blockIdx.x;
    const int c = Lid & 7, u = Lid >> 3;
    const int bh = ((u & 7) << 3) | c;     // bh%8 == c -> XCD-local K/V
    const int pair = u >> 3;               // q-tile pair {pair, 15-pair}, 0..7
    const int h = bh & 15, b = bh >> 4;
    const int l15 = lane & 15, g4 = lane >> 4;
    const float SC2 = 0.125f * 1.44269504f;  // scale * log2e

    {   // bias tables for this head (bf16, 4096-stride, 16B-aligned)
        *(u16x8*)&rbs2a[tid * 8] = *(const u16x8*)&rbT2[(size_t)h * 4096 + tid * 8];
        *(u16x8*)&rbs2a[2048 + tid * 8] = *(const u16x8*)&rbT2[(size_t)h * 4096 + 2048 + tid * 8];
        *(u16x8*)&rbs2b[tid * 8] = *(const u16x8*)&rbT2s[(size_t)h * 4096 + tid * 8];
        *(u16x8*)&rbs2b[2048 + tid * 8] = *(const u16x8*)&rbT2s[(size_t)h * 4096 + 2048 + tid * 8];
    }

    const size_t trow = (size_t)b * T_;
    const int srow = tid >> 2;      // 0..63
    const int sch = tid & 3;        // chunks sch, sch+4
    const int sw = srow & 7;
    u16* pwA = &Ps[wave][0][0];
    u16* pwB = &Ps[wave][1][0];
    // K slice: qkF[(b*T + t)*QKS + 1024 + h*64 + d]
    const u16* kgb = &qkF[(trow + srow) * QKS + 1024 + h * 64];
    const u16* vgb = &Vt[((size_t)bh * DH + srow) * T_];

    // prefetch K/V tile for j0=0 (first tile of half 0)
    u16x8 kv0 = *(const u16x8*)&kgb[sch * 8];
    u16x8 kv1 = *(const u16x8*)&kgb[(sch + 4) * 8];
    u16x8 vv0 = *(const u16x8*)&vgb[sch * 8];
    u16x8 vv1 = *(const u16x8*)&vgb[(sch + 4) * 8];
    // commit tile 0 into buffer 0 (prologue barrier also covers bias tables)
    *(u16x8*)&Ks[0][srow * 64 + ((sch ^ sw) * 8)] = kv0;
    *(u16x8*)&Ks[0][srow * 64 + (((sch + 4) ^ sw) * 8)] = kv1;
    *(u16x8*)&Vs[0][srow * 64 + ((sch ^ sw) * 8)] = vv0;
    *(u16x8*)&Vs[0][srow * 64 + (((sch + 4) ^ sw) * 8)] = vv1;
    __syncthreads();
    int cur = 0;

    for (int half = 0; half < 2; half++) {
        const int blk = half ? 15 - pair : pair;   // 128-row q-tile index
        const int qbA = blk * 128 + wave * 16;     // wave's first 16-row sub-block
        const int qbB = qbA + 64;                  // second sub-block
        bf16x8 aqA[2], aqB[2];
        aqA[0] = *(const bf16x8*)&qkF[(trow + qbA + l15) * QKS + h * 64 + g4 * 8];
        aqA[1] = *(const bf16x8*)&qkF[(trow + qbA + l15) * QKS + h * 64 + 32 + g4 * 8];
        aqB[0] = *(const bf16x8*)&qkF[(trow + qbB + l15) * QKS + h * 64 + g4 * 8];
        aqB[1] = *(const bf16x8*)&qkF[(trow + qbB + l15) * QKS + h * 64 + 32 + g4 * 8];

        // bias base for sub-block A (element index at j0=0, ni=0, r=0); >= 64.
        // Parity is identical for A and B (qbB = qbA + 64) -> one select.
        const int ibA = 2047 - l15 + g4 * 4 - qbA;
        const u32* b32A = (const u32*)((ibA & 1) ? &rbs2b[ibA - 1] : &rbs2a[ibA]);
        const u32* b32B = b32A - 32;   // shift by -64 elements = -32 u32

        f32x4 oaccA[4] = {}, oaccB[4] = {};
        float lA = 0.f, lB = 0.f;

        const int jtmax = 2 * blk + 1;
        for (int jt = 0; jt <= jtmax; jt++) {
            const int j0 = jt * 64;
            // (1) issue next tile's global loads (latency hides under compute)
            const int j0n = (jt + 1 <= jtmax) ? (jt + 1) * 64 : (half == 0 ? 0 : -1);
            if (j0n >= 0) {
                const u16* kg = kgb + (size_t)j0n * QKS;
                const u16* vg = vgb + j0n;
                kv0 = *(const u16x8*)&kg[sch * 8];
                kv1 = *(const u16x8*)&kg[(sch + 4) * 8];
                vv0 = *(const u16x8*)&vg[sch * 8];
                vv1 = *(const u16x8*)&vg[(sch + 4) * 8];
            }
            const u16* KsC = &Ks[cur][0];
            const u16* VsC = &Vs[cur][0];
            // (2) S' = K Q^T for both q-halves: each ak read feeds 2 MFMAs
            f32x4 sA[4], sB[4];
#pragma unroll
            for (int ni = 0; ni < 4; ni++) {
                f32x4 z = {};
                sA[ni] = z;
                sB[ni] = z;
            }
            __builtin_amdgcn_s_setprio(1);
#pragma unroll
            for (int ni = 0; ni < 4; ni++) {
                int arow = ni * 16 + l15;
#pragma unroll
                for (int kk = 0; kk < 2; kk++) {
                    int ch = kk * 4 + g4;
                    bf16x8 ak = *(const bf16x8*)&KsC[arow * 64 + ((ch ^ (arow & 7)) * 8)];
                    sA[ni] = __builtin_amdgcn_mfma_f32_16x16x32_bf16(ak, aqA[kk], sA[ni], 0, 0, 0);
                    sB[ni] = __builtin_amdgcn_mfma_f32_16x16x32_bf16(ak, aqB[kk], sB[ni], 0, 0, 0);
                }
            }
            __builtin_amdgcn_s_setprio(0);
            // softmax (exp2 direct, no max-tracking) + P-write, per half
            const int jo = j0 >> 1;
            {
                float su = 0.f;
#pragma unroll
                for (int ni = 0; ni < 4; ni++) {
                    u32 w0 = b32A[jo + ni * 8];
                    u32 w1 = b32A[jo + ni * 8 + 1];
                    float e0 = exp2f_fast(fmaf(sA[ni][0], SC2, __builtin_bit_cast(float, w0 << 16)));
                    float e1 = exp2f_fast(fmaf(sA[ni][1], SC2, __builtin_bit_cast(float, w0 & 0xffff0000u)));
                    float e2 = exp2f_fast(fmaf(sA[ni][2], SC2, __builtin_bit_cast(float, w1 << 16)));
                    float e3 = exp2f_fast(fmaf(sA[ni][3], SC2, __builtin_bit_cast(float, w1 & 0xffff0000u)));
                    su += (e0 + e1) + (e2 + e3);
                    u16x4 pk;
                    pk[0] = __builtin_bit_cast(u16, (bf16)e0);
                    pk[1] = __builtin_bit_cast(u16, (bf16)e1);
                    pk[2] = __builtin_bit_cast(u16, (bf16)e2);
                    pk[3] = __builtin_bit_cast(u16, (bf16)e3);
                    int colb = ni * 16 + g4 * 4;
                    int ch = colb >> 3, co = colb & 7;
                    *(u16x4*)&pwA[l15 * 64 + ((ch ^ (l15 & 7)) * 8) + co] = pk;
                }
                su += __shfl_xor(su, 16);
                su += __shfl_xor(su, 32);
                lA += su;
            }
            {
                float su = 0.f;
#pragma unroll
                for (int ni = 0; ni < 4; ni++) {
                    u32 w0 = b32B[jo + ni * 8];
                    u32 w1 = b32B[jo + ni * 8 + 1];
                    float e0 = exp2f_fast(fmaf(sB[ni][0], SC2, __builtin_bit_cast(float, w0 << 16)));
                    float e1 = exp2f_fast(fmaf(sB[ni][1], SC2, __builtin_bit_cast(float, w0 & 0xffff0000u)));
                    float e2 = exp2f_fast(fmaf(sB[ni][2], SC2, __builtin_bit_cast(float, w1 << 16)));
                    float e3 = exp2f_fast(fmaf(sB[ni][3], SC2, __builtin_bit_cast(float, w1 & 0xffff0000u)));
                    su += (e0 + e1) + (e2 + e3);
                    u16x4 pk;
                    pk[0] = __builtin_bit_cast(u16, (bf16)e0);
                    pk[1] = __builtin_bit_cast(u16, (bf16)e1);
                    pk[2] = __builtin_bit_cast(u16, (bf16)e2);
                    pk[3] = __builtin_bit_cast(u16, (bf16)e3);
                    int colb = ni * 16 + g4 * 4;
                    int ch = colb >> 3, co = colb & 7;
                    *(u16x4*)&pwB[l15 * 64 + ((ch ^ (l15 & 7)) * 8) + co] = pk;
                }
                su += __shfl_xor(su, 16);
                su += __shfl_xor(su, 32);
                lB += su;
            }
            // PV: each av read feeds 2 MFMAs (both halves)
            bf16x8 bpA[2], bpB[2];
#pragma unroll
            for (int kk = 0; kk < 2; kk++) {
                int ch = kk * 4 + g4;
                int off = l15 * 64 + ((ch ^ (l15 & 7)) * 8);
                bpA[kk] = *(const bf16x8*)&pwA[off];
                bpB[kk] = *(const bf16x8*)&pwB[off];
            }
            __builtin_amdgcn_s_setprio(1);
#pragma unroll
            for (int di = 0; di < 4; di++) {
                int vrow = di * 16 + l15;
#pragma unroll
                for (int kk = 0; kk < 2; kk++) {
                    int ch = kk * 4 + g4;
                    bf16x8 av = *(const bf16x8*)&VsC[vrow * 64 + ((ch ^ (vrow & 7)) * 8)];
                    oaccA[di] = __builtin_amdgcn_mfma_f32_16x16x32_bf16(av, bpA[kk], oaccA[di], 0, 0, 0);
                    oaccB[di] = __builtin_amdgcn_mfma_f32_16x16x32_bf16(av, bpB[kk], oaccB[di], 0, 0, 0);
                }
            }
            __builtin_amdgcn_s_setprio(0);
            // (3) commit next tile into the other buffer, (4) single barrier
            if (j0n >= 0) {
                u16* Kn = &Ks[cur ^ 1][0];
                u16* Vn = &Vs[cur ^ 1][0];
                *(u16x8*)&Kn[srow * 64 + ((sch ^ sw) * 8)] = kv0;
                *(u16x8*)&Kn[srow * 64 + (((sch + 4) ^ sw) * 8)] = kv1;
                *(u16x8*)&Vn[srow * 64 + ((sch ^ sw) * 8)] = vv0;
                *(u16x8*)&Vn[srow * 64 + (((sch + 4) ^ sw) * 8)] = vv1;
            }
            __syncthreads();
            cur ^= 1;
        }
        // normalize + write attnO (b, t, h*64+d) bf16; lane owns q = qb?+l15,
        // d = di*16 + g4*4 + {0..3} -> 4x 8B stores per half
        {
            float inv = 1.0f / lA;
            u16* orow = &O[((size_t)b * T_ + qbA + l15) * (NH * DH) + h * DH];
#pragma unroll
            for (int di = 0; di < 4; di++) {
                u16x4 ov;
#pragma unroll
                for (int r = 0; r < 4; r++)
                    ov[r] = __builtin_bit_cast(u16, (bf16)(oaccA[di][r] * inv));
                *(u16x4*)&orow[di * 16 + g4 * 4] = ov;
            }
        }
        {
            float inv = 1.0f / lB;
            u16* orow = &O[((size_t)b * T_ + qbB + l15) * (NH * DH) + h * DH];
#pragma unroll
            for (int di = 0; di < 4; di++) {
                u16x4 ov;
#pragma unroll
                for (int r = 0; r < 4; r++)
                    ov[r] = __builtin_bit_cast(u16, (bf16)(oaccB[di][r] * inv));
                *(u16x4*)&orow[di * 16 + g4 * 4] = ov;
            }
        }
    }
}

// ---------------- launcher ----------------

extern "C" void kernel_launch(void* const* d_in, const int* in_sizes, int n_in,
                              void* d_out, int out_size, void* d_ws, size_t ws_size,
                              hipStream_t stream) {
    const float* x    = (const float*)d_in[0];
    const float* Wqkv = (const float*)d_in[1];
    const float* W0   = (const float*)d_in[2];
    const float* rb   = (const float*)d_in[3];
    char* ws = (char*)d_ws;

    // ws layout (bytes); no aliasing (xb live until merged GEMM; qkF through flash)
    u16*   xb    = (u16*)(ws + 0);            // 16,777,216
    u16*   WqkvT = (u16*)(ws + 16777216);     //  6,291,456
    u16*   W0T   = (u16*)(ws + 23068672);     //  2,097,152
    u16*   rbT2  = (u16*)(ws + 25165824);     //    131,072 (16 x 4096 bf16)
    u16*   rbT2s = (u16*)(ws + 25296896);     //    131,072 (shifted copy)
    u16*   qkF   = (u16*)(ws + 25427968);     // 33,554,432 (Q,K features, stride 2048)
    u16*   attnO = (u16*)(ws + 58982400);     // 16,777,216
    u16*   Vtb   = (u16*)(ws + 75759616);     // 16,777,216 -> total 92,536,832

    cvt_bf16_k<<<4096, 256, 0, stream>>>(x, xb, (B_ * T_ * DIM) / 8);
    wcvt_t_k<1><<<dim3(NF / 32, DIM / 32), 256, 0, stream>>>(Wqkv, WqkvT, DIM, NF);
    wcvt_t_k<0><<<dim3(DIM / 32, DIM / 32), 256, 0, stream>>>(W0, W0T, DIM, DIM);
    rbt_k<<<(NH * 4096 + 255) / 256, 256, 0, stream>>>(rb, rbT2, rbT2s);

    // merged QKV GEMM: bn<16 -> qkF[b*T+t][k*1024+h*64+d]; bn>=16 -> Vt direct
    gemm_bt_k<1><<<dim3((B_ * T_) / 128, NF / 128), 256, 0, stream>>>(
        xb, WqkvT, qkF, Vtb, B_ * T_, QKS, DIM);

    flash_attn_k<<<512, 256, 0, stream>>>(qkF, Vtb, rbT2, rbT2s, attnO);

    gemm_bt_k<0><<<dim3((B_ * T_) / 128, DIM / 128), 256, 0, stream>>>(
        attnO, W0T, d_out, nullptr, B_ * T_, DIM, DIM);
}